// Round 10
// baseline (9651.460 us; speedup 1.0000x reference)
//
#include <hip/hip_runtime.h>
#include <hip/hip_bf16.h>
#include <cstdint>

#define Hh   1024
#define G3   3072
#define POISON_U 0xFFFFFFFFu

__device__ __forceinline__ float sigmoidf_(float x) { return 1.f / (1.f + __expf(-x)); }

__device__ __forceinline__ float ld_agent(const float* p) {
    return __hip_atomic_load(p, __ATOMIC_RELAXED, __HIP_MEMORY_SCOPE_AGENT);
}
__device__ __forceinline__ void st_agent(float* p, float v) {
    __hip_atomic_store(p, v, __ATOMIC_RELAXED, __HIP_MEMORY_SCOPE_AGENT);
}
__device__ __forceinline__ bool okf(float v) { return __float_as_uint(v) != POISON_U; }

// r3's proven poll discipline: ONE outstanding load, sleep BEFORE each reload
__device__ __forceinline__ float poll1(const float* p) {
    float v = ld_agent(p);
    int guard = 0;
    while (!okf(v)) {
        __builtin_amdgcn_s_sleep(1);
        v = ld_agent(p);
        if (++guard > (1 << 20)) break;   // paranoia: no infinite hang
    }
    return v;
}

// ---------------- gather: x_enc = emb[char_seq], x_dec = emb[[sos]+target[:-1]] ----------------
__global__ __launch_bounds__(128) void gather_emb(const int* __restrict__ char_seq,
    const int* __restrict__ target, const int* __restrict__ sos,
    const float* __restrict__ emb, float* __restrict__ x_enc, float* __restrict__ x_dec)
{
    const int r = blockIdx.x;
    int id; float* dst;
    if (r < 1024) { id = char_seq[r]; dst = x_enc + (size_t)r * 512; }
    else {
        const int rd = r - 1024;
        id = (rd == 0) ? sos[0] : target[rd - 1];
        dst = x_dec + (size_t)rd * 512;
    }
    const float4* src = (const float4*)(emb + (size_t)id * 512);
    ((float4*)dst)[threadIdx.x] = src[threadIdx.x];
}

// ---------------- GEMM: C[M x N] = A[M x K] @ W[N x K]^T + bias[N]  (f32, 64x64 tile) ----------------
__global__ __launch_bounds__(256) void gemm_nt(const float* __restrict__ A,
    const float* __restrict__ W, const float* __restrict__ bias,
    float* __restrict__ C, int M, int N, int K)
{
    __shared__ float As[16][68];
    __shared__ float Ws[16][68];
    const int tid = threadIdx.x;
    const int tx = tid & 15, ty = tid >> 4;
    const int row0 = blockIdx.y * 64, col0 = blockIdx.x * 64;
    const int lr = tid >> 2;          // 0..63
    const int ls = (tid & 3) << 2;    // 0,4,8,12
    float acc[4][4] = {};
    for (int k0 = 0; k0 < K; k0 += 16) {
        const float4 a4 = *(const float4*)(A + (size_t)(row0 + lr) * K + k0 + ls);
        const float4 w4 = *(const float4*)(W + (size_t)(col0 + lr) * K + k0 + ls);
        As[ls + 0][lr] = a4.x; As[ls + 1][lr] = a4.y; As[ls + 2][lr] = a4.z; As[ls + 3][lr] = a4.w;
        Ws[ls + 0][lr] = w4.x; Ws[ls + 1][lr] = w4.y; Ws[ls + 2][lr] = w4.z; Ws[ls + 3][lr] = w4.w;
        __syncthreads();
        #pragma unroll
        for (int k = 0; k < 16; ++k) {
            const float4 a = *(const float4*)&As[k][ty << 2];
            const float4 w = *(const float4*)&Ws[k][tx << 2];
            const float av[4] = {a.x, a.y, a.z, a.w};
            const float wv[4] = {w.x, w.y, w.z, w.w};
            #pragma unroll
            for (int i = 0; i < 4; ++i)
                #pragma unroll
                for (int j = 0; j < 4; ++j)
                    acc[i][j] += av[i] * wv[j];
        }
        __syncthreads();
    }
    const int cc = col0 + (tx << 2);
    #pragma unroll
    for (int i = 0; i < 4; ++i) {
        float4 o;
        o.x = acc[i][0] + bias[cc + 0];
        o.y = acc[i][1] + bias[cc + 1];
        o.z = acc[i][2] + bias[cc + 2];
        o.w = acc[i][3] + bias[cc + 3];
        *(float4*)(C + (size_t)(row0 + (ty << 2) + i) * N + cc) = o;
    }
}

// ---------------- fused 2-layer GRU: register weights + LDS-shared poison-poll dataflow ----------------
// RE-PARAMETRIZED GRID vs r3: 128 WGs x 1024 threads (16 waves/WG, 1 unit/wave).
// WGs 0..63 = layer0 (units wg*16+wv), WGs 64..127 = layer1. Effects:
//  - half as many consumer WGs -> total per-step beyond-L2 poll traffic halves;
//  - 1024 threads cover a full h-row with ONE 4B granule per thread -> L0 fill = 1 RTT
//    (was 2 serial), L1 fill = 2 serial RTTs (was 4).
// Poll discipline, sync structure = r3's validated form, unchanged: 4B granules, one
// outstanding load per thread, sleep-before-reload; fill -> barrier -> compute+store -> barrier
// (trailing barrier drains h-stores via vmcnt(0) before s_barrier and protects the LDS WAR).
// hs rows poisoned 0xFFFFFFFF at launch; producers publish via relaxed agent 4B stores.
__global__ __launch_bounds__(1024) void fused_gru2(
    const float* __restrict__ gx0,
    const float* __restrict__ whh0, const float* __restrict__ bhh0,
    const float* __restrict__ wih1, const float* __restrict__ bih1,
    const float* __restrict__ whh1, const float* __restrict__ bhh1,
    const float* __restrict__ h0i, const float* __restrict__ h1i,
    float* __restrict__ hs0, float* __restrict__ hs1, int S)
{
    __shared__ float shA[Hh];     // L0: h0_prev | L1: x (= hs0[t+1])
    __shared__ float shB[Hh];     // L1 only: h1_prev
    const int tid = threadIdx.x;
    const int wg  = blockIdx.x;
    const int ln = tid & 63;
    const int wv = tid >> 6;                             // 0..15
    const int base = ln << 2;

    if (wg < 64) {
        // ================= layer 0 =================
        const int uu = (wg << 4) + wv;
        float4 wa[3][4];
        #pragma unroll
        for (int g = 0; g < 3; ++g)
            #pragma unroll
            for (int j = 0; j < 4; ++j)
                wa[g][j] = *(const float4*)(whh0 + (size_t)(g * Hh + uu) * Hh + base + (j << 8));
        const float ba_r = bhh0[uu], ba_z = bhh0[Hh + uu], ba_n = bhh0[2 * Hh + uu];

        for (int t = 0; t < S; ++t) {
            // gx row loads issued early (plain loads, overlap the fill)
            const float* gxt = gx0 + (size_t)t * G3 + uu;
            const float xr = gxt[0], xz = gxt[Hh], xn = gxt[2 * Hh];

            if (t == 0) shA[tid] = h0i[tid];
            else        shA[tid] = poll1(hs0 + (size_t)t * Hh + tid);
            __syncthreads();

            const float4* sA = (const float4*)shA;
            float ar = 0.f, az = 0.f, an = 0.f;
            #pragma unroll
            for (int j = 0; j < 4; ++j) {
                const float4 x4 = sA[ln + 64 * j];
                ar += x4.x * wa[0][j].x + x4.y * wa[0][j].y + x4.z * wa[0][j].z + x4.w * wa[0][j].w;
                az += x4.x * wa[1][j].x + x4.y * wa[1][j].y + x4.z * wa[1][j].z + x4.w * wa[1][j].w;
                an += x4.x * wa[2][j].x + x4.y * wa[2][j].y + x4.z * wa[2][j].z + x4.w * wa[2][j].w;
            }
            #pragma unroll
            for (int m = 1; m < 64; m <<= 1) {
                ar += __shfl_xor(ar, m); az += __shfl_xor(az, m); an += __shfl_xor(an, m);
            }
            if (ln == 0) {
                const float rr = sigmoidf_(xr + ar + ba_r);
                const float zz = sigmoidf_(xz + az + ba_z);
                const float nn = tanhf(xn + rr * (an + ba_n));
                const float hnew = (1.f - zz) * nn + zz * shA[uu];
                st_agent(hs0 + (size_t)(t + 1) * Hh + uu, hnew);
            }
            __syncthreads();   // drains stores (vmcnt 0) + protects LDS WAR
        }
    } else {
        // ================= layer 1 =================
        const int uu = ((wg - 64) << 4) + wv;
        float4 wa[3][4], wb[3][4];
        #pragma unroll
        for (int g = 0; g < 3; ++g)
            #pragma unroll
            for (int j = 0; j < 4; ++j) {
                wa[g][j] = *(const float4*)(wih1 + (size_t)(g * Hh + uu) * Hh + base + (j << 8));
                wb[g][j] = *(const float4*)(whh1 + (size_t)(g * Hh + uu) * Hh + base + (j << 8));
            }
        const float ba_r = bih1[uu], ba_z = bih1[Hh + uu], ba_n = bih1[2 * Hh + uu];
        const float bb_r = bhh1[uu], bb_z = bhh1[Hh + uu], bb_n = bhh1[2 * Hh + uu];

        for (int t = 0; t < S; ++t) {
            // serial polls (r3 discipline): x row (the later arrival) first, then h row
            shA[tid] = poll1(hs0 + (size_t)(t + 1) * Hh + tid);
            if (t == 0) shB[tid] = h1i[tid];
            else        shB[tid] = poll1(hs1 + (size_t)t * Hh + tid);
            __syncthreads();

            const float4* sA = (const float4*)shA;
            const float4* sB = (const float4*)shB;
            float ar = 0.f, az = 0.f, an = 0.f, hr = 0.f, hz = 0.f, hn = 0.f;
            #pragma unroll
            for (int j = 0; j < 4; ++j) {
                const float4 x4 = sA[ln + 64 * j];
                const float4 h4 = sB[ln + 64 * j];
                ar += x4.x * wa[0][j].x + x4.y * wa[0][j].y + x4.z * wa[0][j].z + x4.w * wa[0][j].w;
                az += x4.x * wa[1][j].x + x4.y * wa[1][j].y + x4.z * wa[1][j].z + x4.w * wa[1][j].w;
                an += x4.x * wa[2][j].x + x4.y * wa[2][j].y + x4.z * wa[2][j].z + x4.w * wa[2][j].w;
                hr += h4.x * wb[0][j].x + h4.y * wb[0][j].y + h4.z * wb[0][j].z + h4.w * wb[0][j].w;
                hz += h4.x * wb[1][j].x + h4.y * wb[1][j].y + h4.z * wb[1][j].z + h4.w * wb[1][j].w;
                hn += h4.x * wb[2][j].x + h4.y * wb[2][j].y + h4.z * wb[2][j].z + h4.w * wb[2][j].w;
            }
            #pragma unroll
            for (int m = 1; m < 64; m <<= 1) {
                ar += __shfl_xor(ar, m); az += __shfl_xor(az, m); an += __shfl_xor(an, m);
                hr += __shfl_xor(hr, m); hz += __shfl_xor(hz, m); hn += __shfl_xor(hn, m);
            }
            if (ln == 0) {
                const float rr = sigmoidf_((ar + ba_r) + (hr + bb_r));
                const float zz = sigmoidf_((az + ba_z) + (hz + bb_z));
                const float nn = tanhf((an + ba_n) + rr * (hn + bb_n));
                const float hnew = (1.f - zz) * nn + zz * shB[uu];
                st_agent(hs1 + (size_t)(t + 1) * Hh + uu, hnew);
            }
            __syncthreads();   // drains stores (vmcnt 0) + protects LDS WAR
        }
    }
}

// ---------------- char_states_out: out[t][0:1024]=hs_d0[t+1], out[t][1024:2048]=hs_d1[t+1] ----------------
__global__ __launch_bounds__(256) void copy_states(const float* __restrict__ hs0,
    const float* __restrict__ hs1, float* __restrict__ out)
{
    const int f = blockIdx.x * 256 + threadIdx.x;  // float4 index, total 262144
    const int t = f >> 9;
    const int c = f & 511;
    const float* src = (c < 256) ? (hs0 + (((size_t)t + 1) << 10) + (c << 2))
                                 : (hs1 + (((size_t)t + 1) << 10) + ((c - 256) << 2));
    *(float4*)(out + ((size_t)f << 2)) = *(const float4*)src;
}

// ---------------- label heads on char_scores[last] + zero padding ----------------
__global__ __launch_bounds__(256) void labels_kernel(const float* __restrict__ scores,
    const float* __restrict__ w0, const float* __restrict__ b0,
    const float* __restrict__ w1, const float* __restrict__ b1,
    const float* __restrict__ w2, const float* __restrict__ b2,
    float* __restrict__ out)
{
    __shared__ float sl[Hh];
    const int tid = threadIdx.x;
    for (int i = tid; i < Hh; i += 256) sl[i] = scores[(size_t)511 * Hh + i];
    for (int i = tid; i < 240; i += 256) out[i] = 0.f;
    __syncthreads();
    const int wv = tid >> 6, ln = tid & 63;
    for (int o = wv; o < 80; o += 4) {
        const float* w; float bb; float* dst;
        if (o < 50)      { w = w0 + (size_t)o * Hh;        bb = b0[o];      dst = out + o; }
        else if (o < 70) { w = w1 + (size_t)(o - 50) * Hh; bb = b1[o - 50]; dst = out + 150 + (o - 50); }
        else             { w = w2 + (size_t)(o - 70) * Hh; bb = b2[o - 70]; dst = out + 210 + (o - 70); }
        float s = 0.f;
        #pragma unroll
        for (int i = 0; i < 4; ++i) {
            const int k = (ln << 2) + (i << 8);
            const float4 ww = *(const float4*)&w[k];
            const float4 l4 = *(const float4*)&sl[k];
            s += ww.x * l4.x + ww.y * l4.y + ww.z * l4.z + ww.w * l4.w;
        }
        #pragma unroll
        for (int m = 1; m < 64; m <<= 1) s += __shfl_xor(s, m);
        if (ln == 0) *dst = s + bb;
    }
}

extern "C" void kernel_launch(void* const* d_in, const int* in_sizes, int n_in,
                              void* d_out, int out_size, void* d_ws, size_t ws_size,
                              hipStream_t stream)
{
    (void)in_sizes; (void)n_in; (void)out_size; (void)ws_size;
    const int*   char_seq  = (const int*)d_in[0];
    const int*   target    = (const int*)d_in[1];
    const float* enc_state = (const float*)d_in[2];
    const float* emb       = (const float*)d_in[3];
    const float* enc_wih0  = (const float*)d_in[4];
    const float* enc_whh0  = (const float*)d_in[5];
    const float* enc_bih0  = (const float*)d_in[6];
    const float* enc_bhh0  = (const float*)d_in[7];
    const float* enc_wih1  = (const float*)d_in[8];
    const float* enc_whh1  = (const float*)d_in[9];
    const float* enc_bih1  = (const float*)d_in[10];
    const float* enc_bhh1  = (const float*)d_in[11];
    const float* dec_wih0  = (const float*)d_in[12];
    const float* dec_whh0  = (const float*)d_in[13];
    const float* dec_bih0  = (const float*)d_in[14];
    const float* dec_bhh0  = (const float*)d_in[15];
    const float* dec_wih1  = (const float*)d_in[16];
    const float* dec_whh1  = (const float*)d_in[17];
    const float* dec_bih1  = (const float*)d_in[18];
    const float* dec_bhh1  = (const float*)d_in[19];
    const float* out_w     = (const float*)d_in[20];
    const float* out_b     = (const float*)d_in[21];
    const float* cls_w0    = (const float*)d_in[22];
    const float* cls_b0    = (const float*)d_in[23];
    const float* cls_w1    = (const float*)d_in[24];
    const float* cls_b1    = (const float*)d_in[25];
    const float* cls_w2    = (const float*)d_in[26];
    const float* cls_b2    = (const float*)d_in[27];
    const int*   sos       = (const int*)d_in[28];

    float* ws    = (float*)d_ws;
    float* x_enc = ws;                                   // 1024*512
    float* x_dec = x_enc + 1024 * 512;                   // 512*512
    float* gx    = x_dec + 512 * 512;                    // 1024*3072 (enc L0, then dec L0)
    float* hs_e0 = gx + 1024 * 3072;                     // 1025*1024 (row 0 unused)
    float* hs_e1 = hs_e0 + 1025 * 1024;                  // 1025*1024
    float* hs_d0 = hs_e1 + 1025 * 1024;                  // 513*1024
    float* hs_d1 = hs_d0 + 513 * 1024;                   // 513*1024

    float* out        = (float*)d_out;
    float* out_scores = out;                             // 512*1024
    float* out_states = out + 512 * 1024;                // 512*2048
    float* out_labels = out_states + 512 * 2048;         // 240

    // poison all hs rows: the data is its own ready-flag (re-done every launch -> replay-safe)
    hipMemsetAsync(hs_e0, 0xFF, (size_t)(1025 + 1025 + 513 + 513) * 1024 * sizeof(float), stream);

    gather_emb<<<1536, 128, 0, stream>>>(char_seq, target, sos, emb, x_enc, x_dec);

    // encoder: gx for layer0, then fused 2-layer dataflow recurrence
    gemm_nt<<<dim3(48, 16), 256, 0, stream>>>(x_enc, enc_wih0, enc_bih0, gx, 1024, 3072, 512);
    fused_gru2<<<128, 1024, 0, stream>>>(gx, enc_whh0, enc_bhh0,
                                         enc_wih1, enc_bih1, enc_whh1, enc_bhh1,
                                         enc_state, enc_state + 1024,
                                         hs_e0, hs_e1, 1024);

    // decoder: gx for layer0 (reuses gx buffer), fused 2-layer dataflow recurrence
    gemm_nt<<<dim3(48, 8), 256, 0, stream>>>(x_dec, dec_wih0, dec_bih0, gx, 512, 3072, 512);
    fused_gru2<<<128, 1024, 0, stream>>>(gx, dec_whh0, dec_bhh0,
                                         dec_wih1, dec_bih1, dec_whh1, dec_bhh1,
                                         hs_e0 + 1024 * 1024, hs_e1 + 1024 * 1024,
                                         hs_d0, hs_d1, 512);

    // char_scores -> d_out region 0
    gemm_nt<<<dim3(16, 8), 256, 0, stream>>>(hs_d1 + 1024, out_w, out_b, out_scores, 512, 1024, 1024);
    // char_states_out
    copy_states<<<1024, 256, 0, stream>>>(hs_d0, hs_d1, out_states);
    // label heads (+ padding zeros)
    labels_kernel<<<1, 256, 0, stream>>>(out_scores, cls_w0, cls_b0, cls_w1, cls_b1, cls_w2, cls_b2, out_labels);
}

// Round 11
// 4255.292 us; speedup vs baseline: 2.2681x; 2.2681x over previous
//
#include <hip/hip_runtime.h>
#include <hip/hip_bf16.h>
#include <cstdint>

#define Hh   1024
#define G3   3072
#define POISON_U 0xFFFFFFFFu

__device__ __forceinline__ float sigmoidf_(float x) { return 1.f / (1.f + __expf(-x)); }

__device__ __forceinline__ float ld_agent(const float* p) {
    return __hip_atomic_load(p, __ATOMIC_RELAXED, __HIP_MEMORY_SCOPE_AGENT);
}
__device__ __forceinline__ void st_agent(float* p, float v) {
    __hip_atomic_store(p, v, __ATOMIC_RELAXED, __HIP_MEMORY_SCOPE_AGENT);
}
__device__ __forceinline__ float poll_val(const float* p) {
    float v = ld_agent(p);
    int guard = 0;
    while (__float_as_uint(v) == POISON_U) {
        __builtin_amdgcn_s_sleep(1);
        v = ld_agent(p);
        if (++guard > (1 << 20)) break;   // paranoia: no infinite hang
    }
    return v;
}

// ---------------- gather: x_enc = emb[char_seq], x_dec = emb[[sos]+target[:-1]] ----------------
__global__ __launch_bounds__(128) void gather_emb(const int* __restrict__ char_seq,
    const int* __restrict__ target, const int* __restrict__ sos,
    const float* __restrict__ emb, float* __restrict__ x_enc, float* __restrict__ x_dec)
{
    const int r = blockIdx.x;
    int id; float* dst;
    if (r < 1024) { id = char_seq[r]; dst = x_enc + (size_t)r * 512; }
    else {
        const int rd = r - 1024;
        id = (rd == 0) ? sos[0] : target[rd - 1];
        dst = x_dec + (size_t)rd * 512;
    }
    const float4* src = (const float4*)(emb + (size_t)id * 512);
    ((float4*)dst)[threadIdx.x] = src[threadIdx.x];
}

// ---------------- GEMM: C[M x N] = A[M x K] @ W[N x K]^T + bias[N]  (f32, 64x64 tile) ----------------
__global__ __launch_bounds__(256) void gemm_nt(const float* __restrict__ A,
    const float* __restrict__ W, const float* __restrict__ bias,
    float* __restrict__ C, int M, int N, int K)
{
    __shared__ float As[16][68];
    __shared__ float Ws[16][68];
    const int tid = threadIdx.x;
    const int tx = tid & 15, ty = tid >> 4;
    const int row0 = blockIdx.y * 64, col0 = blockIdx.x * 64;
    const int lr = tid >> 2;          // 0..63
    const int ls = (tid & 3) << 2;    // 0,4,8,12
    float acc[4][4] = {};
    for (int k0 = 0; k0 < K; k0 += 16) {
        const float4 a4 = *(const float4*)(A + (size_t)(row0 + lr) * K + k0 + ls);
        const float4 w4 = *(const float4*)(W + (size_t)(col0 + lr) * K + k0 + ls);
        As[ls + 0][lr] = a4.x; As[ls + 1][lr] = a4.y; As[ls + 2][lr] = a4.z; As[ls + 3][lr] = a4.w;
        Ws[ls + 0][lr] = w4.x; Ws[ls + 1][lr] = w4.y; Ws[ls + 2][lr] = w4.z; Ws[ls + 3][lr] = w4.w;
        __syncthreads();
        #pragma unroll
        for (int k = 0; k < 16; ++k) {
            const float4 a = *(const float4*)&As[k][ty << 2];
            const float4 w = *(const float4*)&Ws[k][tx << 2];
            const float av[4] = {a.x, a.y, a.z, a.w};
            const float wv[4] = {w.x, w.y, w.z, w.w};
            #pragma unroll
            for (int i = 0; i < 4; ++i)
                #pragma unroll
                for (int j = 0; j < 4; ++j)
                    acc[i][j] += av[i] * wv[j];
        }
        __syncthreads();
    }
    const int cc = col0 + (tx << 2);
    #pragma unroll
    for (int i = 0; i < 4; ++i) {
        float4 o;
        o.x = acc[i][0] + bias[cc + 0];
        o.y = acc[i][1] + bias[cc + 1];
        o.z = acc[i][2] + bias[cc + 2];
        o.w = acc[i][3] + bias[cc + 3];
        *(float4*)(C + (size_t)(row0 + (ty << 2) + i) * N + cc) = o;
    }
}

// ---------------- fused 2-layer GRU recurrence: register weights + poison-poll dataflow ----------------
// EXACT r3 champion structure (benched 4260 us, absmax 0.0078, replay-stable):
// Grid: 256 WGs x 512 threads. WGs 0..127 = layer0 (1 unit per wave), 128..255 = layer1.
// No barriers/flags between WGs: hs rows are poisoned (0xFFFFFFFF) at launch; writers publish
// h elements with relaxed agent-scope 4B stores; readers poll the data itself (one outstanding
// load per thread, sleep BEFORE each reload) -- the validated fabric-friendly discipline.
// Pipeline: L0 at iter t consumes hs0[t] -> produces hs0[t+1];
//           L1 at iter t consumes hs0[t+1], hs1[t] -> produces hs1[t+1].
// Per step: fill LDS (serial polls) -> barrier -> gates+store -> barrier (LDS WAR + store drain).
__global__ __launch_bounds__(512, 2) void fused_gru2(
    const float* __restrict__ gx0,
    const float* __restrict__ whh0, const float* __restrict__ bhh0,
    const float* __restrict__ wih1, const float* __restrict__ bih1,
    const float* __restrict__ whh1, const float* __restrict__ bhh1,
    const float* __restrict__ h0i, const float* __restrict__ h1i,
    float* __restrict__ hs0, float* __restrict__ hs1, int S)
{
    __shared__ float sh0[Hh];
    __shared__ float sh1[Hh];
    const int tid = threadIdx.x;
    const int wg  = blockIdx.x;
    const bool isL1 = (wg >= 128);
    const int ln = tid & 63;
    const int wv = tid >> 6;                             // 0..7
    const int uu = ((isL1 ? wg - 128 : wg) << 3) + wv;   // hidden unit 0..1023

    // --- loop-invariant weights into VGPRs ---
    float4 wa[3][4], wb[3][4];
    const float* WA = isL1 ? wih1 : whh0;
    #pragma unroll
    for (int g = 0; g < 3; ++g)
        #pragma unroll
        for (int j = 0; j < 4; ++j)
            wa[g][j] = *(const float4*)(WA + (size_t)(g * Hh + uu) * Hh + ((ln + 64 * j) << 2));
    if (isL1) {
        #pragma unroll
        for (int g = 0; g < 3; ++g)
            #pragma unroll
            for (int j = 0; j < 4; ++j)
                wb[g][j] = *(const float4*)(whh1 + (size_t)(g * Hh + uu) * Hh + ((ln + 64 * j) << 2));
    } else {
        #pragma unroll
        for (int g = 0; g < 3; ++g)
            #pragma unroll
            for (int j = 0; j < 4; ++j)
                wb[g][j] = make_float4(0.f, 0.f, 0.f, 0.f);
    }
    const float* BA = isL1 ? bih1 : bhh0;
    const float ba_r = BA[uu], ba_z = BA[Hh + uu], ba_n = BA[2 * Hh + uu];
    const float bb_r = isL1 ? bhh1[uu] : 0.f;
    const float bb_z = isL1 ? bhh1[Hh + uu] : 0.f;
    const float bb_n = isL1 ? bhh1[2 * Hh + uu] : 0.f;

    const float4* s0f4 = (const float4*)sh0;
    const float4* s1f4 = (const float4*)sh1;

    for (int t = 0; t < S; ++t) {
        // gx row loads (L0 only) issued early to overlap with the fill/poll
        float xr = 0.f, xz = 0.f, xn = 0.f;
        if (!isL1 && ln == 0) {
            const float* gxt = gx0 + (size_t)t * G3 + uu;
            xr = gxt[0]; xz = gxt[Hh]; xn = gxt[2 * Hh];
        }

        // --- fill LDS with required state rows (poison-poll on in-flight rows) ---
        if (!isL1) {
            if (t == 0) {
                sh0[tid] = h0i[tid]; sh0[tid + 512] = h0i[tid + 512];
            } else {
                const float* row = hs0 + (size_t)t * Hh;
                const float v0 = poll_val(&row[tid]);
                const float v1 = poll_val(&row[tid + 512]);
                sh0[tid] = v0; sh0[tid + 512] = v1;
            }
        } else {
            const float* rx = hs0 + (size_t)(t + 1) * Hh;      // always in-flight
            const float v0 = poll_val(&rx[tid]);
            const float v1 = poll_val(&rx[tid + 512]);
            sh0[tid] = v0; sh0[tid + 512] = v1;
            if (t == 0) {
                sh1[tid] = h1i[tid]; sh1[tid + 512] = h1i[tid + 512];
            } else {
                const float* rh = hs1 + (size_t)t * Hh;
                const float w0 = poll_val(&rh[tid]);
                const float w1 = poll_val(&rh[tid + 512]);
                sh1[tid] = w0; sh1[tid + 512] = w1;
            }
        }
        __syncthreads();

        // --- gates ---
        float ar = 0.f, az = 0.f, an = 0.f;       // wa · (L0: h0_prev | L1: h0-as-x)
        float hr = 0.f, hz = 0.f, hn = 0.f;       // wb · h1_prev (L1 only)
        #pragma unroll
        for (int j = 0; j < 4; ++j) {
            const float4 x4 = s0f4[ln + 64 * j];
            ar += x4.x * wa[0][j].x + x4.y * wa[0][j].y + x4.z * wa[0][j].z + x4.w * wa[0][j].w;
            az += x4.x * wa[1][j].x + x4.y * wa[1][j].y + x4.z * wa[1][j].z + x4.w * wa[1][j].w;
            an += x4.x * wa[2][j].x + x4.y * wa[2][j].y + x4.z * wa[2][j].z + x4.w * wa[2][j].w;
        }
        if (isL1) {
            #pragma unroll
            for (int j = 0; j < 4; ++j) {
                const float4 h4 = s1f4[ln + 64 * j];
                hr += h4.x * wb[0][j].x + h4.y * wb[0][j].y + h4.z * wb[0][j].z + h4.w * wb[0][j].w;
                hz += h4.x * wb[1][j].x + h4.y * wb[1][j].y + h4.z * wb[1][j].z + h4.w * wb[1][j].w;
                hn += h4.x * wb[2][j].x + h4.y * wb[2][j].y + h4.z * wb[2][j].z + h4.w * wb[2][j].w;
            }
        }
        #pragma unroll
        for (int m = 1; m < 64; m <<= 1) {
            ar += __shfl_xor(ar, m); az += __shfl_xor(az, m); an += __shfl_xor(an, m);
            if (isL1) { hr += __shfl_xor(hr, m); hz += __shfl_xor(hz, m); hn += __shfl_xor(hn, m); }
        }
        if (ln == 0) {
            float rr, zz, nn, hprev;
            if (!isL1) {
                rr = sigmoidf_(xr + ar + ba_r);
                zz = sigmoidf_(xz + az + ba_z);
                nn = tanhf(xn + rr * (an + ba_n));
                hprev = sh0[uu];
            } else {
                rr = sigmoidf_((ar + ba_r) + (hr + bb_r));
                zz = sigmoidf_((az + ba_z) + (hz + bb_z));
                nn = tanhf((an + ba_n) + rr * (hn + bb_n));
                hprev = sh1[uu];
            }
            const float hnew = (1.f - zz) * nn + zz * hprev;
            st_agent((isL1 ? hs1 : hs0) + (size_t)(t + 1) * Hh + uu, hnew);
        }
        __syncthreads();   // WAR: next iter's fill overwrites sh0/sh1; also drains h-stores
    }
}

// ---------------- char_states_out: out[t][0:1024]=hs_d0[t+1], out[t][1024:2048]=hs_d1[t+1] ----------------
__global__ __launch_bounds__(256) void copy_states(const float* __restrict__ hs0,
    const float* __restrict__ hs1, float* __restrict__ out)
{
    const int f = blockIdx.x * 256 + threadIdx.x;  // float4 index, total 262144
    const int t = f >> 9;
    const int c = f & 511;
    const float* src = (c < 256) ? (hs0 + (((size_t)t + 1) << 10) + (c << 2))
                                 : (hs1 + (((size_t)t + 1) << 10) + ((c - 256) << 2));
    *(float4*)(out + ((size_t)f << 2)) = *(const float4*)src;
}

// ---------------- label heads on char_scores[last] + zero padding ----------------
__global__ __launch_bounds__(256) void labels_kernel(const float* __restrict__ scores,
    const float* __restrict__ w0, const float* __restrict__ b0,
    const float* __restrict__ w1, const float* __restrict__ b1,
    const float* __restrict__ w2, const float* __restrict__ b2,
    float* __restrict__ out)
{
    __shared__ float sl[Hh];
    const int tid = threadIdx.x;
    for (int i = tid; i < Hh; i += 256) sl[i] = scores[(size_t)511 * Hh + i];
    for (int i = tid; i < 240; i += 256) out[i] = 0.f;
    __syncthreads();
    const int wv = tid >> 6, ln = tid & 63;
    for (int o = wv; o < 80; o += 4) {
        const float* w; float bb; float* dst;
        if (o < 50)      { w = w0 + (size_t)o * Hh;        bb = b0[o];      dst = out + o; }
        else if (o < 70) { w = w1 + (size_t)(o - 50) * Hh; bb = b1[o - 50]; dst = out + 150 + (o - 50); }
        else             { w = w2 + (size_t)(o - 70) * Hh; bb = b2[o - 70]; dst = out + 210 + (o - 70); }
        float s = 0.f;
        #pragma unroll
        for (int i = 0; i < 4; ++i) {
            const int k = (ln << 2) + (i << 8);
            const float4 ww = *(const float4*)&w[k];
            const float4 l4 = *(const float4*)&sl[k];
            s += ww.x * l4.x + ww.y * l4.y + ww.z * l4.z + ww.w * l4.w;
        }
        #pragma unroll
        for (int m = 1; m < 64; m <<= 1) s += __shfl_xor(s, m);
        if (ln == 0) *dst = s + bb;
    }
}

extern "C" void kernel_launch(void* const* d_in, const int* in_sizes, int n_in,
                              void* d_out, int out_size, void* d_ws, size_t ws_size,
                              hipStream_t stream)
{
    (void)in_sizes; (void)n_in; (void)out_size; (void)ws_size;
    const int*   char_seq  = (const int*)d_in[0];
    const int*   target    = (const int*)d_in[1];
    const float* enc_state = (const float*)d_in[2];
    const float* emb       = (const float*)d_in[3];
    const float* enc_wih0  = (const float*)d_in[4];
    const float* enc_whh0  = (const float*)d_in[5];
    const float* enc_bih0  = (const float*)d_in[6];
    const float* enc_bhh0  = (const float*)d_in[7];
    const float* enc_wih1  = (const float*)d_in[8];
    const float* enc_whh1  = (const float*)d_in[9];
    const float* enc_bih1  = (const float*)d_in[10];
    const float* enc_bhh1  = (const float*)d_in[11];
    const float* dec_wih0  = (const float*)d_in[12];
    const float* dec_whh0  = (const float*)d_in[13];
    const float* dec_bih0  = (const float*)d_in[14];
    const float* dec_bhh0  = (const float*)d_in[15];
    const float* dec_wih1  = (const float*)d_in[16];
    const float* dec_whh1  = (const float*)d_in[17];
    const float* dec_bih1  = (const float*)d_in[18];
    const float* dec_bhh1  = (const float*)d_in[19];
    const float* out_w     = (const float*)d_in[20];
    const float* out_b     = (const float*)d_in[21];
    const float* cls_w0    = (const float*)d_in[22];
    const float* cls_b0    = (const float*)d_in[23];
    const float* cls_w1    = (const float*)d_in[24];
    const float* cls_b1    = (const float*)d_in[25];
    const float* cls_w2    = (const float*)d_in[26];
    const float* cls_b2    = (const float*)d_in[27];
    const int*   sos       = (const int*)d_in[28];

    float* ws    = (float*)d_ws;
    float* x_enc = ws;                                   // 1024*512
    float* x_dec = x_enc + 1024 * 512;                   // 512*512
    float* gx    = x_dec + 512 * 512;                    // 1024*3072 (enc L0, then dec L0)
    float* hs_e0 = gx + 1024 * 3072;                     // 1025*1024 (row 0 unused)
    float* hs_e1 = hs_e0 + 1025 * 1024;                  // 1025*1024
    float* hs_d0 = hs_e1 + 1025 * 1024;                  // 513*1024
    float* hs_d1 = hs_d0 + 513 * 1024;                   // 513*1024

    float* out        = (float*)d_out;
    float* out_scores = out;                             // 512*1024
    float* out_states = out + 512 * 1024;                // 512*2048
    float* out_labels = out_states + 512 * 2048;         // 240

    // poison all hs rows: the data is its own ready-flag (re-done every launch -> replay-safe)
    hipMemsetAsync(hs_e0, 0xFF, (size_t)(1025 + 1025 + 513 + 513) * 1024 * sizeof(float), stream);

    gather_emb<<<1536, 128, 0, stream>>>(char_seq, target, sos, emb, x_enc, x_dec);

    // encoder: gx for layer0, then fused 2-layer dataflow recurrence
    gemm_nt<<<dim3(48, 16), 256, 0, stream>>>(x_enc, enc_wih0, enc_bih0, gx, 1024, 3072, 512);
    fused_gru2<<<256, 512, 0, stream>>>(gx, enc_whh0, enc_bhh0,
                                        enc_wih1, enc_bih1, enc_whh1, enc_bhh1,
                                        enc_state, enc_state + 1024,
                                        hs_e0, hs_e1, 1024);

    // decoder: gx for layer0 (reuses gx buffer), fused 2-layer dataflow recurrence
    gemm_nt<<<dim3(48, 8), 256, 0, stream>>>(x_dec, dec_wih0, dec_bih0, gx, 512, 3072, 512);
    fused_gru2<<<256, 512, 0, stream>>>(gx, dec_whh0, dec_bhh0,
                                        dec_wih1, dec_bih1, dec_whh1, dec_bhh1,
                                        hs_e0 + 1024 * 1024, hs_e1 + 1024 * 1024,
                                        hs_d0, hs_d1, 512);

    // char_scores -> d_out region 0
    gemm_nt<<<dim3(16, 8), 256, 0, stream>>>(hs_d1 + 1024, out_w, out_b, out_scores, 512, 1024, 1024);
    // char_states_out
    copy_states<<<1024, 256, 0, stream>>>(hs_d0, hs_d1, out_states);
    // label heads (+ padding zeros)
    labels_kernel<<<1, 256, 0, stream>>>(out_scores, cls_w0, cls_b0, cls_w1, cls_b1, cls_w2, cls_b2, out_labels);
}